// Round 7
// baseline (37079.718 us; speedup 1.0000x reference)
//
#include <hip/hip_runtime.h>
#include <cstdint>

// VAN checkerboard sampler, LEVEL=0 (odd,odd positions), B=4096, L=16, H=32, K=5.
// R7 = R6 (two batch elements per 1024-thread block) with the s_xf init bug fixed:
// each group has 784 halo entries but only 512 group-local threads; R6's
// `if (tl < 784)` left entries 512..783 uninitialized (absmax 3.3). Now a strided
// loop covers all 784.
//
// R6 design (audited bit-exact vs reference):
//   - waves 0-7 own elem A, waves 8-15 elem B; __syncthreads() serves both
//   - each thread runs TWO conv2 chains (ics 2*slot, 2*slot+1):
//       pair = accA + accB            == reference's even+odd shfl merge order
//       r = pair_wl + pair_{wl+8}     (commuted vs ref; IEEE add commutative)
//     8 waves write-only to s_r: the old s_buf add-stage (+barrier) is gone
//   - phase3: two passes reproduce the 16-virtual-wave butterfly exactly
//   - LDS 92.4KB -> 1 block/CU -> 128-reg budget; forced live set ~95 floats
//     (50 weights + 2x15 accs + row) pushes the allocator off the 32-reg squeeze
//     that kept R0-R5 at ~1.9x essential VALU (accvgpr/scratch churn)
// All per-output fma chains keep exact (tr asc, kx asc) order => bit-exact.

struct U2 { uint32_t x, y; };

// JAX Threefry-2x32 (20 rounds), matches jax/_src/prng.py
__device__ __forceinline__ U2 tf2x32(uint32_t k0, uint32_t k1, uint32_t x0, uint32_t x1) {
  uint32_t k2 = k0 ^ k1 ^ 0x1BD11BDAu;
#define TFROT(r) { x0 += x1; x1 = (x1 << (r)) | (x1 >> (32 - (r))); x1 ^= x0; }
  x0 += k0; x1 += k1;
  TFROT(13) TFROT(15) TFROT(26) TFROT(6)
  x0 += k1; x1 += k2 + 1u;
  TFROT(17) TFROT(29) TFROT(16) TFROT(24)
  x0 += k2; x1 += k0 + 2u;
  TFROT(13) TFROT(15) TFROT(26) TFROT(6)
  x0 += k0; x1 += k1 + 3u;
  TFROT(17) TFROT(29) TFROT(16) TFROT(24)
  x0 += k1; x1 += k2 + 4u;
  TFROT(13) TFROT(15) TFROT(26) TFROT(6)
  x0 += k2; x1 += k0 + 5u;
#undef TFROT
  return {x0, x1};
}

__device__ __forceinline__ float lrelu(float v) { return fmaxf(v, 0.1f * v); }

__launch_bounds__(1024, 4)
__global__ void van_kernel(const float* __restrict__ gx,
                           const float* __restrict__ gw1, const float* __restrict__ gb1,
                           const float* __restrict__ gw2, const float* __restrict__ gb2,
                           const float* __restrict__ gw3, const float* __restrict__ gb3,
                           float* __restrict__ out, int B) {
  // per-group (=per batch elem) state; x field has +/-6 circular halo
  __shared__ __align__(16) float s_xf[2][28 * 28];
  __shared__ __align__(16) float s_h1[2][32][9][12];  // h1 tile, row pitch 12
  __shared__ __align__(16) float s_w1[800];
  __shared__ __align__(16) float s_w3[800];
  __shared__ __align__(16) float s_r[2][8][800];      // r_v = pair_v + pair_{v+8}
  __shared__ float s_b1[32], s_b2[32];
  __shared__ float s_u[2][64];
  __shared__ float s_c3[2][16];

  const int tid  = threadIdx.x;
  const int g    = tid >> 9;              // group (elem) 0/1
  const int tl   = tid & 511;             // group-local tid
  const int lane = tid & 63;
  const int wl   = (tid >> 6) & 7;        // wave index within group, 0..7
  const int oc   = lane & 31;
  const int slot = wl + 8 * (lane >> 5);  // 0..15: this thread's ic-pair id
  const int icA  = 2 * slot, icB = 2 * slot + 1;
  const int bg   = blockIdx.x * 2 + g;

  // ---------------- init ----------------
  const float b3v = gb3[0];
  float w2a[25], w2b[25];
  {
    const float* pa = gw2 + (oc * 32 + icA) * 25;  // w2[oc][icA][ky][kx]
    const float* pb = gw2 + (oc * 32 + icB) * 25;
    #pragma unroll
    for (int k = 0; k < 25; ++k) { w2a[k] = pa[k]; w2b[k] = pb[k]; }
  }
  if (tid < 800) { s_w1[tid] = gw1[tid]; s_w3[tid] = gw3[tid]; }
  if (tid < 32)  { s_b1[tid] = gb1[tid]; s_b2[tid] = gb2[tid]; }
  for (int t = tl; t < 784; t += 512) {   // 784 halo entries, 512 group threads
    int rr = t / 28, cc = t - rr * 28;
    int fy = (rr - 6) & 15, fx = (cc - 6) & 15;
    s_xf[g][t] = gx[bg * 256 + fy * 16 + fx];
  }
  if (tl < 64) {
    // jax_threefry_partitionable=True: key_s = tf(root=(0,42),(0,s)); bits = x^y of tf(key_s,(0,b))
    U2 key = tf2x32(0u, 42u, 0u, (uint32_t)tl);
    U2 tt  = tf2x32(key.x, key.y, 0u, (uint32_t)bg);
    uint32_t bits = tt.x ^ tt.y;
    s_u[g][tl] = __uint_as_float(0x3F800000u | (bits >> 9)) - 1.0f;
  }
  float logq = 0.f;   // meaningful on tl==0 of each group
  __syncthreads();

  #pragma unroll 1
  for (int s = 0; s < 64; ++s) {
    const int i = 2 * (s >> 3) + 1;
    const int j = 2 * (s & 7) + 1;

    // ---- phase 1: h1 tile (9x9x32); tile (r,c) <-> field (i-4+r, j-4+c) ----
    if (tl < 288) {
      const int t_ic = tl / 9;
      const int r    = tl - t_ic * 9;
      const float bb = s_b1[t_ic];
      float a[9];
      #pragma unroll
      for (int c = 0; c < 9; ++c) a[c] = bb;
      #pragma unroll
      for (int ky = 0; ky < 5; ++ky) {
        const float* xr = &s_xf[g][(i + r + ky) * 28 + j];
        float xv[13];
        #pragma unroll
        for (int m = 0; m < 13; ++m) xv[m] = xr[m];
        #pragma unroll
        for (int kx = 0; kx < 5; ++kx) {
          const float w = s_w1[t_ic * 25 + ky * 5 + kx];
          #pragma unroll
          for (int c = 0; c < 9; ++c) a[c] = fmaf(xv[c + kx], w, a[c]);
        }
      }
      #pragma unroll
      for (int c = 0; c < 9; ++c) s_h1[g][t_ic][r][c] = lrelu(a[c]);
    }
    __syncthreads();

    // ---- phase 2: conv2, two chains per thread, 2 position passes ----
    // Each chain's per-output fma order: (tr asc == ky asc, kx asc) -- identical
    // to reference. pair = accA + accB (even ic first, as the old shfl merge).
    // r = pair + shfl_xor(pair,32): lane<32 holds pair_v + pair_{v+8}
    // (reference computed pair_{v+8} + pair_v; IEEE add commutative => same bits).
#define CHAIN_PASS(HP, W, ACC, DYLO, DYHI, TRLO, TRHI, NACC)                       \
    {                                                                              \
      _Pragma("unroll")                                                            \
      for (int p = 0; p < (NACC); ++p) (ACC)[p] = 0.f;                             \
      _Pragma("unroll")                                                            \
      for (int tr = (TRLO); tr <= (TRHI); ++tr) {                                  \
        const float4* rp = (const float4*)(&(HP)[tr][0]);                          \
        const float4 ra = rp[0], rb = rp[1];                                       \
        const float r8 = (HP)[tr][8];                                              \
        const float row[9] = {ra.x, ra.y, ra.z, ra.w, rb.x, rb.y, rb.z, rb.w, r8}; \
        _Pragma("unroll")                                                          \
        for (int dy = (DYLO); dy <= (DYHI); ++dy) {                                \
          const int ky = tr - dy;                                                  \
          if (ky < 0 || ky > 4) continue;   /* folds at compile time */            \
          _Pragma("unroll")                                                        \
          for (int kx = 0; kx < 5; ++kx) {                                         \
            const float w = (W)[ky * 5 + kx];                                      \
            _Pragma("unroll")                                                      \
            for (int dx = 0; dx < 5; ++dx)                                         \
              (ACC)[(dy - (DYLO)) * 5 + dx] = fmaf(row[dx + kx], w,                \
                                                   (ACC)[(dy - (DYLO)) * 5 + dx]); \
          }                                                                        \
        }                                                                          \
      }                                                                            \
    }

    const float (*hpA)[12] = s_h1[g][icA];
    const float (*hpB)[12] = s_h1[g][icB];

    {   // pass A: dy {0,1,2}, p = 0..14, rows tr 0..6
      float accA[15], accB[15];
      CHAIN_PASS(hpA, w2a, accA, 0, 2, 0, 6, 15)
      CHAIN_PASS(hpB, w2b, accB, 0, 2, 0, 6, 15)
      #pragma unroll
      for (int p = 0; p < 15; ++p) {
        float pair = accA[p] + accB[p];
        float r = pair + __shfl_xor(pair, 32, 64);
        if (lane < 32) s_r[g][wl][p * 32 + oc] = r;
      }
    }
    {   // pass B: dy {3,4}, p = 15..24, rows tr 3..8
      float accA[10], accB[10];
      CHAIN_PASS(hpA, w2a, accA, 3, 4, 3, 8, 10)
      CHAIN_PASS(hpB, w2b, accB, 3, 4, 3, 8, 10)
      #pragma unroll
      for (int p = 0; p < 10; ++p) {
        float pair = accA[p] + accB[p];
        float r = pair + __shfl_xor(pair, 32, 64);
        if (lane < 32) s_r[g][wl][(p + 15) * 32 + oc] = r;
      }
    }
#undef CHAIN_PASS
    __syncthreads();

    // ---- phase 3: a2 sum (fixed order), lrelu, conv3 partials ----
    // Two passes reproduce the original 16-virtual-wave butterfly exactly:
    // pass 0 -> virtual tids 0..511 (c3[0..7]), pass 1 -> 512..1023 (c3[8..15]).
    #pragma unroll
    for (int pass = 0; pass < 2; ++pass) {
      const int vt = tl + 512 * pass;
      float v3 = 0.f;
      if (vt < 800) {
        float t = 0.f;
        #pragma unroll
        for (int v = 0; v < 8; ++v) t += s_r[g][v][vt];
        t += s_b2[vt & 31];
        const float h2 = lrelu(t);
        v3 = h2 * s_w3[(vt & 31) * 25 + (vt >> 5)];   // w3[oc][pos]
      }
      #pragma unroll
      for (int m = 32; m >= 1; m >>= 1) v3 += __shfl_xor(v3, m, 64);
      if (lane == 0) s_c3[g][wl + 8 * pass] = v3;
    }
    __syncthreads();

    // ---- phase 4: sample (tl==0 of each group), update x halo copies ----
    if (tl == 0) {
      float logit = b3v;
      #pragma unroll
      for (int v = 0; v < 16; ++v) logit += s_c3[g][v];
      const float pr   = 1.f / (1.f + expf(-logit));
      const float u    = s_u[g][s];
      const float samp = (u < pr) ? 1.f : -1.f;
      const int r1 = i + 6, c1 = j + 6;
      const int r2 = (i < 6) ? i + 22 : ((i >= 10) ? i - 10 : r1);
      const int c2 = (j < 6) ? j + 22 : ((j >= 10) ? j - 10 : c1);
      s_xf[g][r1 * 28 + c1] = samp; s_xf[g][r1 * 28 + c2] = samp;
      s_xf[g][r2 * 28 + c1] = samp; s_xf[g][r2 * 28 + c2] = samp;
      logq += (samp > 0.f) ? logf(pr + 1e-7f) : logf(1.f - pr + 1e-7f);
    }
    __syncthreads();
  }

  // ---------------- output ----------------
  if (tl < 256)
    out[bg * 256 + tl] = s_xf[g][((tl >> 4) + 6) * 28 + (tl & 15) + 6];
  if (tl == 0)
    out[B * 256 + bg] = logq;
}

extern "C" void kernel_launch(void* const* d_in, const int* in_sizes, int n_in,
                              void* d_out, int out_size, void* d_ws, size_t ws_size,
                              hipStream_t stream) {
  const float* gx  = (const float*)d_in[0];
  const float* gw1 = (const float*)d_in[1];
  const float* gb1 = (const float*)d_in[2];
  const float* gw2 = (const float*)d_in[3];
  const float* gb2 = (const float*)d_in[4];
  const float* gw3 = (const float*)d_in[5];
  const float* gb3 = (const float*)d_in[6];
  float* out = (float*)d_out;
  const int B = in_sizes[0] / 256;

  hipLaunchKernelGGL(van_kernel, dim3(B / 2), dim3(1024), 0, stream,
                     gx, gw1, gb1, gw2, gb2, gw3, gb3, out, B);
}

// Round 8
// 37070.316 us; speedup vs baseline: 1.0003x; 1.0003x over previous
//
#include <hip/hip_runtime.h>
#include <cstdint>

// VAN checkerboard sampler, LEVEL=0 (odd,odd positions), B=4096, L=16, H=32, K=5.
// R8 = R7 (two batch elements per 1024-thread block, bit-exact, passed) plus
// amdgpu_waves_per_eu(4,4). R7's allocator targeted 8 waves/EU (VGPR=64) even
// though 92.7KB LDS already caps the CU at 1 block = 4 waves/EU, so ~30 floats/
// thread spilled to scratch: FETCH 42GB, WRITE 29GB, VALUBusy 14%, dur 37ms.
// Pinning waves/EU to 4 gives the allocator its real budget (128 regs) for the
// ~95-float live set (50 weights + 2x15 accs + row 9).
//
// Design (audited bit-exact vs reference):
//   - waves 0-7 own elem A, waves 8-15 elem B; __syncthreads() serves both
//   - each thread runs TWO conv2 chains (ics 2*slot, 2*slot+1):
//       pair = accA + accB            == reference's even+odd shfl merge order
//       r = pair_wl + pair_{wl+8}     (commuted vs ref; IEEE add commutative)
//     8 waves write-only to s_r: the old s_buf add-stage (+barrier) is gone
//   - phase3: two passes reproduce the 16-virtual-wave butterfly exactly
// All per-output fma chains keep exact (tr asc, kx asc) order => bit-exact.

struct U2 { uint32_t x, y; };

// JAX Threefry-2x32 (20 rounds), matches jax/_src/prng.py
__device__ __forceinline__ U2 tf2x32(uint32_t k0, uint32_t k1, uint32_t x0, uint32_t x1) {
  uint32_t k2 = k0 ^ k1 ^ 0x1BD11BDAu;
#define TFROT(r) { x0 += x1; x1 = (x1 << (r)) | (x1 >> (32 - (r))); x1 ^= x0; }
  x0 += k0; x1 += k1;
  TFROT(13) TFROT(15) TFROT(26) TFROT(6)
  x0 += k1; x1 += k2 + 1u;
  TFROT(17) TFROT(29) TFROT(16) TFROT(24)
  x0 += k2; x1 += k0 + 2u;
  TFROT(13) TFROT(15) TFROT(26) TFROT(6)
  x0 += k0; x1 += k1 + 3u;
  TFROT(17) TFROT(29) TFROT(16) TFROT(24)
  x0 += k1; x1 += k2 + 4u;
  TFROT(13) TFROT(15) TFROT(26) TFROT(6)
  x0 += k2; x1 += k0 + 5u;
#undef TFROT
  return {x0, x1};
}

__device__ __forceinline__ float lrelu(float v) { return fmaxf(v, 0.1f * v); }

__global__ __launch_bounds__(1024) __attribute__((amdgpu_waves_per_eu(4, 4)))
void van_kernel(const float* __restrict__ gx,
                const float* __restrict__ gw1, const float* __restrict__ gb1,
                const float* __restrict__ gw2, const float* __restrict__ gb2,
                const float* __restrict__ gw3, const float* __restrict__ gb3,
                float* __restrict__ out, int B) {
  // per-group (=per batch elem) state; x field has +/-6 circular halo
  __shared__ __align__(16) float s_xf[2][28 * 28];
  __shared__ __align__(16) float s_h1[2][32][9][12];  // h1 tile, row pitch 12
  __shared__ __align__(16) float s_w1[800];
  __shared__ __align__(16) float s_w3[800];
  __shared__ __align__(16) float s_r[2][8][800];      // r_v = pair_v + pair_{v+8}
  __shared__ float s_b1[32], s_b2[32];
  __shared__ float s_u[2][64];
  __shared__ float s_c3[2][16];

  const int tid  = threadIdx.x;
  const int g    = tid >> 9;              // group (elem) 0/1
  const int tl   = tid & 511;             // group-local tid
  const int lane = tid & 63;
  const int wl   = (tid >> 6) & 7;        // wave index within group, 0..7
  const int oc   = lane & 31;
  const int slot = wl + 8 * (lane >> 5);  // 0..15: this thread's ic-pair id
  const int icA  = 2 * slot, icB = 2 * slot + 1;
  const int bg   = blockIdx.x * 2 + g;

  // ---------------- init ----------------
  const float b3v = gb3[0];
  float w2a[25], w2b[25];
  {
    const float* pa = gw2 + (oc * 32 + icA) * 25;  // w2[oc][icA][ky][kx]
    const float* pb = gw2 + (oc * 32 + icB) * 25;
    #pragma unroll
    for (int k = 0; k < 25; ++k) { w2a[k] = pa[k]; w2b[k] = pb[k]; }
  }
  if (tid < 800) { s_w1[tid] = gw1[tid]; s_w3[tid] = gw3[tid]; }
  if (tid < 32)  { s_b1[tid] = gb1[tid]; s_b2[tid] = gb2[tid]; }
  for (int t = tl; t < 784; t += 512) {   // 784 halo entries, 512 group threads
    int rr = t / 28, cc = t - rr * 28;
    int fy = (rr - 6) & 15, fx = (cc - 6) & 15;
    s_xf[g][t] = gx[bg * 256 + fy * 16 + fx];
  }
  if (tl < 64) {
    // jax_threefry_partitionable=True: key_s = tf(root=(0,42),(0,s)); bits = x^y of tf(key_s,(0,b))
    U2 key = tf2x32(0u, 42u, 0u, (uint32_t)tl);
    U2 tt  = tf2x32(key.x, key.y, 0u, (uint32_t)bg);
    uint32_t bits = tt.x ^ tt.y;
    s_u[g][tl] = __uint_as_float(0x3F800000u | (bits >> 9)) - 1.0f;
  }
  float logq = 0.f;   // meaningful on tl==0 of each group
  __syncthreads();

  #pragma unroll 1
  for (int s = 0; s < 64; ++s) {
    const int i = 2 * (s >> 3) + 1;
    const int j = 2 * (s & 7) + 1;

    // ---- phase 1: h1 tile (9x9x32); tile (r,c) <-> field (i-4+r, j-4+c) ----
    if (tl < 288) {
      const int t_ic = tl / 9;
      const int r    = tl - t_ic * 9;
      const float bb = s_b1[t_ic];
      float a[9];
      #pragma unroll
      for (int c = 0; c < 9; ++c) a[c] = bb;
      #pragma unroll
      for (int ky = 0; ky < 5; ++ky) {
        const float* xr = &s_xf[g][(i + r + ky) * 28 + j];
        float xv[13];
        #pragma unroll
        for (int m = 0; m < 13; ++m) xv[m] = xr[m];
        #pragma unroll
        for (int kx = 0; kx < 5; ++kx) {
          const float w = s_w1[t_ic * 25 + ky * 5 + kx];
          #pragma unroll
          for (int c = 0; c < 9; ++c) a[c] = fmaf(xv[c + kx], w, a[c]);
        }
      }
      #pragma unroll
      for (int c = 0; c < 9; ++c) s_h1[g][t_ic][r][c] = lrelu(a[c]);
    }
    __syncthreads();

    // ---- phase 2: conv2, two chains per thread, 2 position passes ----
    // Each chain's per-output fma order: (tr asc == ky asc, kx asc) -- identical
    // to reference. pair = accA + accB (even ic first, as the old shfl merge).
    // r = pair + shfl_xor(pair,32): lane<32 holds pair_v + pair_{v+8}
    // (reference computed pair_{v+8} + pair_v; IEEE add commutative => same bits).
#define CHAIN_PASS(HP, W, ACC, DYLO, DYHI, TRLO, TRHI, NACC)                       \
    {                                                                              \
      _Pragma("unroll")                                                            \
      for (int p = 0; p < (NACC); ++p) (ACC)[p] = 0.f;                             \
      _Pragma("unroll")                                                            \
      for (int tr = (TRLO); tr <= (TRHI); ++tr) {                                  \
        const float4* rp = (const float4*)(&(HP)[tr][0]);                          \
        const float4 ra = rp[0], rb = rp[1];                                       \
        const float r8 = (HP)[tr][8];                                              \
        const float row[9] = {ra.x, ra.y, ra.z, ra.w, rb.x, rb.y, rb.z, rb.w, r8}; \
        _Pragma("unroll")                                                          \
        for (int dy = (DYLO); dy <= (DYHI); ++dy) {                                \
          const int ky = tr - dy;                                                  \
          if (ky < 0 || ky > 4) continue;   /* folds at compile time */            \
          _Pragma("unroll")                                                        \
          for (int kx = 0; kx < 5; ++kx) {                                         \
            const float w = (W)[ky * 5 + kx];                                      \
            _Pragma("unroll")                                                      \
            for (int dx = 0; dx < 5; ++dx)                                         \
              (ACC)[(dy - (DYLO)) * 5 + dx] = fmaf(row[dx + kx], w,                \
                                                   (ACC)[(dy - (DYLO)) * 5 + dx]); \
          }                                                                        \
        }                                                                          \
      }                                                                            \
    }

    const float (*hpA)[12] = s_h1[g][icA];
    const float (*hpB)[12] = s_h1[g][icB];

    {   // pass A: dy {0,1,2}, p = 0..14, rows tr 0..6
      float accA[15], accB[15];
      CHAIN_PASS(hpA, w2a, accA, 0, 2, 0, 6, 15)
      CHAIN_PASS(hpB, w2b, accB, 0, 2, 0, 6, 15)
      #pragma unroll
      for (int p = 0; p < 15; ++p) {
        float pair = accA[p] + accB[p];
        float r = pair + __shfl_xor(pair, 32, 64);
        if (lane < 32) s_r[g][wl][p * 32 + oc] = r;
      }
    }
    {   // pass B: dy {3,4}, p = 15..24, rows tr 3..8
      float accA[10], accB[10];
      CHAIN_PASS(hpA, w2a, accA, 3, 4, 3, 8, 10)
      CHAIN_PASS(hpB, w2b, accB, 3, 4, 3, 8, 10)
      #pragma unroll
      for (int p = 0; p < 10; ++p) {
        float pair = accA[p] + accB[p];
        float r = pair + __shfl_xor(pair, 32, 64);
        if (lane < 32) s_r[g][wl][(p + 15) * 32 + oc] = r;
      }
    }
#undef CHAIN_PASS
    __syncthreads();

    // ---- phase 3: a2 sum (fixed order), lrelu, conv3 partials ----
    // Two passes reproduce the original 16-virtual-wave butterfly exactly:
    // pass 0 -> virtual tids 0..511 (c3[0..7]), pass 1 -> 512..1023 (c3[8..15]).
    #pragma unroll
    for (int pass = 0; pass < 2; ++pass) {
      const int vt = tl + 512 * pass;
      float v3 = 0.f;
      if (vt < 800) {
        float t = 0.f;
        #pragma unroll
        for (int v = 0; v < 8; ++v) t += s_r[g][v][vt];
        t += s_b2[vt & 31];
        const float h2 = lrelu(t);
        v3 = h2 * s_w3[(vt & 31) * 25 + (vt >> 5)];   // w3[oc][pos]
      }
      #pragma unroll
      for (int m = 32; m >= 1; m >>= 1) v3 += __shfl_xor(v3, m, 64);
      if (lane == 0) s_c3[g][wl + 8 * pass] = v3;
    }
    __syncthreads();

    // ---- phase 4: sample (tl==0 of each group), update x halo copies ----
    if (tl == 0) {
      float logit = b3v;
      #pragma unroll
      for (int v = 0; v < 16; ++v) logit += s_c3[g][v];
      const float pr   = 1.f / (1.f + expf(-logit));
      const float u    = s_u[g][s];
      const float samp = (u < pr) ? 1.f : -1.f;
      const int r1 = i + 6, c1 = j + 6;
      const int r2 = (i < 6) ? i + 22 : ((i >= 10) ? i - 10 : r1);
      const int c2 = (j < 6) ? j + 22 : ((j >= 10) ? j - 10 : c1);
      s_xf[g][r1 * 28 + c1] = samp; s_xf[g][r1 * 28 + c2] = samp;
      s_xf[g][r2 * 28 + c1] = samp; s_xf[g][r2 * 28 + c2] = samp;
      logq += (samp > 0.f) ? logf(pr + 1e-7f) : logf(1.f - pr + 1e-7f);
    }
    __syncthreads();
  }

  // ---------------- output ----------------
  if (tl < 256)
    out[bg * 256 + tl] = s_xf[g][((tl >> 4) + 6) * 28 + (tl & 15) + 6];
  if (tl == 0)
    out[B * 256 + bg] = logq;
}

extern "C" void kernel_launch(void* const* d_in, const int* in_sizes, int n_in,
                              void* d_out, int out_size, void* d_ws, size_t ws_size,
                              hipStream_t stream) {
  const float* gx  = (const float*)d_in[0];
  const float* gw1 = (const float*)d_in[1];
  const float* gb1 = (const float*)d_in[2];
  const float* gw2 = (const float*)d_in[3];
  const float* gb2 = (const float*)d_in[4];
  const float* gw3 = (const float*)d_in[5];
  const float* gb3 = (const float*)d_in[6];
  float* out = (float*)d_out;
  const int B = in_sizes[0] / 256;

  hipLaunchKernelGGL(van_kernel, dim3(B / 2), dim3(1024), 0, stream,
                     gx, gw1, gb1, gw2, gb2, gw3, gb3, out, B);
}

// Round 9
// 5556.374 us; speedup vs baseline: 6.6734x; 6.6717x over previous
//
#include <hip/hip_runtime.h>
#include <cstdint>

// VAN checkerboard sampler, LEVEL=0 (odd,odd positions), B=4096, L=16, H=32, K=5.
// One 1024-thread block per batch element; all 64 autoregressive steps in-kernel.
// Deterministic reductions only (graph replay must revalidate bit-identically).
//
// R9 = R5 (3-pass conv2, bit-exact, passed) + EXPLICIT AGPR pinning of w2r[25].
// Constraint learned in R0-R8: at 1024 threads this toolchain caps every wave at
// 64 unified regs (32 arch + 32 acc) no matter what launch_bounds/waves_per_eu
// says (R8's amdgpu_waves_per_eu(4,4) was byte-for-byte inert; R7 spilled 42GB).
// R4/R5's remaining ~1.9x VALU junk = compiler shuttling the 25 read-only weights
// through AGPR/scratch blindly. Fix: pin w2r into AGPRs via inline asm --
// v_accvgpr_write_b32 once at init, v_accvgpr_read_b32 at each unrolled weight-use
// site (125/thread-step, +20% VALU, vs ~90% junk). Arch live drops to ~27
// (10 acc + 9 row + w-temp + addr) -> fits the 32 arch regs cleanly, no scratch.
// accvgpr moves are bit-exact; FMA chain order (tr asc == ky asc, kx asc) and all
// reduction orders unchanged => absmax 0.0.

struct U2 { uint32_t x, y; };

// JAX Threefry-2x32 (20 rounds), matches jax/_src/prng.py
__device__ __forceinline__ U2 tf2x32(uint32_t k0, uint32_t k1, uint32_t x0, uint32_t x1) {
  uint32_t k2 = k0 ^ k1 ^ 0x1BD11BDAu;
#define TFROT(r) { x0 += x1; x1 = (x1 << (r)) | (x1 >> (32 - (r))); x1 ^= x0; }
  x0 += k0; x1 += k1;
  TFROT(13) TFROT(15) TFROT(26) TFROT(6)
  x0 += k1; x1 += k2 + 1u;
  TFROT(17) TFROT(29) TFROT(16) TFROT(24)
  x0 += k2; x1 += k0 + 2u;
  TFROT(13) TFROT(15) TFROT(26) TFROT(6)
  x0 += k0; x1 += k1 + 3u;
  TFROT(17) TFROT(29) TFROT(16) TFROT(24)
  x0 += k1; x1 += k2 + 4u;
  TFROT(13) TFROT(15) TFROT(26) TFROT(6)
  x0 += k2; x1 += k0 + 5u;
#undef TFROT
  return {x0, x1};
}

__device__ __forceinline__ float lrelu(float v) { return fmaxf(v, 0.1f * v); }

__launch_bounds__(1024, 8)
__global__ void van_kernel(const float* __restrict__ gx,
                           const float* __restrict__ gw1, const float* __restrict__ gb1,
                           const float* __restrict__ gw2, const float* __restrict__ gb2,
                           const float* __restrict__ gw3, const float* __restrict__ gb3,
                           float* __restrict__ out, int B) {
  // x field with +/-6 circular halo: array row t <-> field row (t-6)&15
  __shared__ __align__(16) float s_xf[28 * 28];
  __shared__ __align__(16) float s_h1[32][9][12];   // h1 tile, row pitch 12 (16B aligned rows)
  __shared__ __align__(16) float s_w1[800];
  __shared__ __align__(16) float s_w3[800];
  __shared__ __align__(16) float s_buf[8][800];     // reduction tree buffers
  __shared__ float s_b1[32], s_b2[32];
  __shared__ float s_u[64];                          // per-step uniforms for this batch elem
  __shared__ float s_c3[16];                         // per-wave conv3 partials

  const int tid  = threadIdx.x;
  const int bg   = blockIdx.x;
  const int lane = tid & 63;
  const int wv   = tid >> 6;
  const int oc   = tid & 31;   // conv2 out-channel of this thread
  const int ic   = tid >> 5;   // conv2 in-channel of this thread

  // ---------------- init ----------------
  const float b3v = gb3[0];
  // w2 weights pinned in AGPRs: written once, read per unrolled use site.
  float w2r[25];
  {
    const float* p = gw2 + (oc * 32 + ic) * 25;   // w2[oc][ic][ky][kx]
    #pragma unroll
    for (int k = 0; k < 25; ++k) {
      float pv = p[k];
      asm volatile("v_accvgpr_write_b32 %0, %1" : "=a"(w2r[k]) : "v"(pv));
    }
  }
  if (tid < 800) { s_w1[tid] = gw1[tid]; s_w3[tid] = gw3[tid]; }
  if (tid < 32)  { s_b1[tid] = gb1[tid]; s_b2[tid] = gb2[tid]; }
  if (tid < 784) {
    int rr = tid / 28, cc = tid - rr * 28;
    int fy = (rr - 6) & 15, fx = (cc - 6) & 15;
    s_xf[tid] = gx[bg * 256 + fy * 16 + fx];
  }
  if (tid < 64) {
    // jax_threefry_partitionable=True conventions:
    // key_s = threefry(root=(0,42), (0, s)); bits(b) = x^y of threefry(key_s, (0, b))
    U2 key = tf2x32(0u, 42u, 0u, (uint32_t)tid);
    U2 tt  = tf2x32(key.x, key.y, 0u, (uint32_t)bg);
    uint32_t bits = tt.x ^ tt.y;
    s_u[tid] = __uint_as_float(0x3F800000u | (bits >> 9)) - 1.0f;
  }
  float logq = 0.f;   // only thread 0's copy is meaningful
  __syncthreads();

  #pragma unroll 1
  for (int s = 0; s < 64; ++s) {
    const int i = 2 * (s >> 3) + 1;
    const int j = 2 * (s & 7) + 1;

    // ---- phase 1: h1 tile (9x9x32) from x; tile (r,c) <-> field (i-4+r, j-4+c) ----
    if (tid < 288) {
      const int t_ic = tid / 9;
      const int r    = tid - t_ic * 9;
      const float bb = s_b1[t_ic];
      float a[9];
      #pragma unroll
      for (int c = 0; c < 9; ++c) a[c] = bb;
      #pragma unroll
      for (int ky = 0; ky < 5; ++ky) {
        const float* xr = &s_xf[(i + r + ky) * 28 + j];   // field row i-6+r+ky, cols j-6..j+6
        float xv[13];
        #pragma unroll
        for (int m = 0; m < 13; ++m) xv[m] = xr[m];
        #pragma unroll
        for (int kx = 0; kx < 5; ++kx) {
          const float w = s_w1[t_ic * 25 + ky * 5 + kx];
          #pragma unroll
          for (int c = 0; c < 9; ++c) a[c] = fmaf(xv[c + kx], w, a[c]);
        }
      }
      #pragma unroll
      for (int c = 0; c < 9; ++c) s_h1[t_ic][r][c] = lrelu(a[c]);
    }
    __syncthreads();

    // ---- phase 2: conv2 at 25 positions, 3 passes (10/10/5 accs) ----
    // Per-pass: all waves compute; wv>=8 bank into s_buf; sync; wv<8 add in.
    // Pass p-ranges are disjoint so pass N+1's banking can't race pass N's adds.
    // Weight at each unrolled (tr,dy,kx) site comes from its AGPR via one
    // v_accvgpr_read (volatile: prevents CSE from hoisting weights into VGPRs).
#define CONV2_PASS(DYLO, DYHI, TRLO, TRHI, NACC)                                   \
    {                                                                              \
      float acc[NACC];                                                             \
      _Pragma("unroll")                                                            \
      for (int p = 0; p < (NACC); ++p) acc[p] = 0.f;                               \
      _Pragma("unroll")                                                            \
      for (int tr = (TRLO); tr <= (TRHI); ++tr) {                                  \
        const float4* rp = (const float4*)(&s_h1[ic][tr][0]);                      \
        const float4 ra = rp[0], rb = rp[1];                                       \
        const float r8 = s_h1[ic][tr][8];                                          \
        const float row[9] = {ra.x, ra.y, ra.z, ra.w, rb.x, rb.y, rb.z, rb.w, r8}; \
        _Pragma("unroll")                                                          \
        for (int dy = (DYLO); dy <= (DYHI); ++dy) {                                \
          const int ky = tr - dy;                                                  \
          if (ky < 0 || ky > 4) continue;   /* folds at compile time */            \
          _Pragma("unroll")                                                        \
          for (int kx = 0; kx < 5; ++kx) {                                         \
            float w;                                                               \
            asm volatile("v_accvgpr_read_b32 %0, %1"                               \
                         : "=v"(w) : "a"(w2r[ky * 5 + kx]));                       \
            _Pragma("unroll")                                                      \
            for (int dx = 0; dx < 5; ++dx)                                         \
              acc[(dy - (DYLO)) * 5 + dx] = fmaf(row[dx + kx], w,                  \
                                                 acc[(dy - (DYLO)) * 5 + dx]);     \
          }                                                                        \
        }                                                                          \
      }                                                                            \
      _Pragma("unroll")                                                            \
      for (int p = 0; p < (NACC); ++p) acc[p] += __shfl_xor(acc[p], 32, 64);       \
      if (wv >= 8 && lane < 32) {                                                  \
        _Pragma("unroll")                                                          \
        for (int p = 0; p < (NACC); ++p)                                           \
          s_buf[wv - 8][((DYLO) * 5 + p) * 32 + lane] = acc[p];                    \
      }                                                                            \
      __syncthreads();                                                             \
      if (wv < 8 && lane < 32) {                                                   \
        _Pragma("unroll")                                                          \
        for (int p = 0; p < (NACC); ++p)                                           \
          s_buf[wv][((DYLO) * 5 + p) * 32 + lane] += acc[p];                       \
      }                                                                            \
    }

    CONV2_PASS(0, 1, 0, 5, 10)   // p = 0..9,   rows 0..5
    CONV2_PASS(2, 3, 2, 7, 10)   // p = 10..19, rows 2..7
    CONV2_PASS(4, 4, 4, 8, 5)    // p = 20..24, rows 4..8
#undef CONV2_PASS
    __syncthreads();

    // ---- phase 3: final a2 sum (fixed order), lrelu, conv3 partials ----
    float v3 = 0.f;
    if (tid < 800) {
      float t = 0.f;
      #pragma unroll
      for (int v = 0; v < 8; ++v) t += s_buf[v][tid];
      t += s_b2[tid & 31];
      const float h2 = lrelu(t);
      v3 = h2 * s_w3[(tid & 31) * 25 + (tid >> 5)];   // w3[oc][pos]
    }
    #pragma unroll
    for (int m = 32; m >= 1; m >>= 1) v3 += __shfl_xor(v3, m, 64);
    if (lane == 0) s_c3[wv] = v3;
    __syncthreads();

    // ---- phase 4: sample (thread 0), update x field halo copies ----
    if (tid == 0) {
      float logit = b3v;
      #pragma unroll
      for (int v = 0; v < 16; ++v) logit += s_c3[v];
      const float pr   = 1.f / (1.f + expf(-logit));
      const float u    = s_u[s];
      const float samp = (u < pr) ? 1.f : -1.f;
      const int r1 = i + 6, c1 = j + 6;
      const int r2 = (i < 6) ? i + 22 : ((i >= 10) ? i - 10 : r1);
      const int c2 = (j < 6) ? j + 22 : ((j >= 10) ? j - 10 : c1);
      s_xf[r1 * 28 + c1] = samp; s_xf[r1 * 28 + c2] = samp;
      s_xf[r2 * 28 + c1] = samp; s_xf[r2 * 28 + c2] = samp;
      logq += (samp > 0.f) ? logf(pr + 1e-7f) : logf(1.f - pr + 1e-7f);
    }
    __syncthreads();
  }

  // ---------------- output ----------------
  if (tid < 256)
    out[bg * 256 + tid] = s_xf[((tid >> 4) + 6) * 28 + (tid & 15) + 6];
  if (tid == 0)
    out[B * 256 + bg] = logq;
}

extern "C" void kernel_launch(void* const* d_in, const int* in_sizes, int n_in,
                              void* d_out, int out_size, void* d_ws, size_t ws_size,
                              hipStream_t stream) {
  const float* gx  = (const float*)d_in[0];
  const float* gw1 = (const float*)d_in[1];
  const float* gb1 = (const float*)d_in[2];
  const float* gw2 = (const float*)d_in[3];
  const float* gb2 = (const float*)d_in[4];
  const float* gw3 = (const float*)d_in[5];
  const float* gb3 = (const float*)d_in[6];
  float* out = (float*)d_out;
  const int B = in_sizes[0] / 256;

  hipLaunchKernelGGL(van_kernel, dim3(B), dim3(1024), 0, stream,
                     gx, gw1, gb1, gw2, gb2, gw3, gb3, out, B);
}

// Round 10
// 5286.605 us; speedup vs baseline: 7.0139x; 1.0510x over previous
//
#include <hip/hip_runtime.h>
#include <cstdint>

// VAN checkerboard sampler, LEVEL=0 (odd,odd positions), B=4096, L=16, H=32, K=5.
// One 1024-thread block per batch element; all 64 autoregressive steps in-kernel.
// Deterministic reductions only (graph replay must revalidate bit-identically).
//
// R10 = R4 (2-pass conv2, best at 4996us) with structural slot trims. R9 proved
// R4 was already ~97% issue-efficient (removing all spill made it SLOWER because
// forced accvgpr reads added slots; compiler already used AGPR-direct operands).
// So: cut instruction count, not spill.
//  - mul-first-tap: each acc's first contribution (ky=0,kx=0) is acc = row*w
//    (fmaf(a,b,0) == a*b bitwise) -> the 25 acc-init movs are gone.
//  - write-only 16-bank merge: s_buf[16][800]; every wave writes its ic-pairsum,
//    the read-modify-write add stage and BOTH mid-pass barriers are gone.
//    Phase3 sums (b[v+8] + b[v]) ascending == R4's stored+add then t+=chain
//    (one commuted IEEE add -> bit-identical). 4 barriers/step instead of 6.
//  - LDS 75.1KB; 2 blocks/CU still fit (150.3 <= 160KB).
// All per-output fma chains keep exact (tr asc == ky asc, kx asc) order.

struct U2 { uint32_t x, y; };

// JAX Threefry-2x32 (20 rounds), matches jax/_src/prng.py
__device__ __forceinline__ U2 tf2x32(uint32_t k0, uint32_t k1, uint32_t x0, uint32_t x1) {
  uint32_t k2 = k0 ^ k1 ^ 0x1BD11BDAu;
#define TFROT(r) { x0 += x1; x1 = (x1 << (r)) | (x1 >> (32 - (r))); x1 ^= x0; }
  x0 += k0; x1 += k1;
  TFROT(13) TFROT(15) TFROT(26) TFROT(6)
  x0 += k1; x1 += k2 + 1u;
  TFROT(17) TFROT(29) TFROT(16) TFROT(24)
  x0 += k2; x1 += k0 + 2u;
  TFROT(13) TFROT(15) TFROT(26) TFROT(6)
  x0 += k0; x1 += k1 + 3u;
  TFROT(17) TFROT(29) TFROT(16) TFROT(24)
  x0 += k1; x1 += k2 + 4u;
  TFROT(13) TFROT(15) TFROT(26) TFROT(6)
  x0 += k2; x1 += k0 + 5u;
#undef TFROT
  return {x0, x1};
}

__device__ __forceinline__ float lrelu(float v) { return fmaxf(v, 0.1f * v); }

__launch_bounds__(1024, 8)
__global__ void van_kernel(const float* __restrict__ gx,
                           const float* __restrict__ gw1, const float* __restrict__ gb1,
                           const float* __restrict__ gw2, const float* __restrict__ gb2,
                           const float* __restrict__ gw3, const float* __restrict__ gb3,
                           float* __restrict__ out, int B) {
  // x field with +/-6 circular halo: array row t <-> field row (t-6)&15
  __shared__ __align__(16) float s_xf[28 * 28];
  __shared__ __align__(16) float s_h1[32][9][12];   // h1 tile, row pitch 12 (16B aligned rows)
  __shared__ __align__(16) float s_w1[800];
  __shared__ __align__(16) float s_w3[800];
  __shared__ __align__(16) float s_buf[16][800];    // bank w = ic-pairsum of wave w
  __shared__ float s_b1[32], s_b2[32];
  __shared__ float s_u[64];                          // per-step uniforms for this batch elem
  __shared__ float s_c3[16];                         // per-wave conv3 partials

  const int tid  = threadIdx.x;
  const int bg   = blockIdx.x;
  const int lane = tid & 63;
  const int wv   = tid >> 6;
  const int oc   = tid & 31;   // conv2 out-channel of this thread
  const int ic   = tid >> 5;   // conv2 in-channel of this thread

  // ---------------- init ----------------
  const float b3v = gb3[0];
  float w2r[25];
  {
    const float* p = gw2 + (oc * 32 + ic) * 25;   // w2[oc][ic][ky][kx]
    #pragma unroll
    for (int k = 0; k < 25; ++k) w2r[k] = p[k];
  }
  if (tid < 800) { s_w1[tid] = gw1[tid]; s_w3[tid] = gw3[tid]; }
  if (tid < 32)  { s_b1[tid] = gb1[tid]; s_b2[tid] = gb2[tid]; }
  if (tid < 784) {
    int rr = tid / 28, cc = tid - rr * 28;
    int fy = (rr - 6) & 15, fx = (cc - 6) & 15;
    s_xf[tid] = gx[bg * 256 + fy * 16 + fx];
  }
  if (tid < 64) {
    // jax_threefry_partitionable=True conventions:
    // key_s = threefry(root=(0,42), (0, s)); bits(b) = x^y of threefry(key_s, (0, b))
    U2 key = tf2x32(0u, 42u, 0u, (uint32_t)tid);
    U2 tt  = tf2x32(key.x, key.y, 0u, (uint32_t)bg);
    uint32_t bits = tt.x ^ tt.y;
    s_u[tid] = __uint_as_float(0x3F800000u | (bits >> 9)) - 1.0f;
  }
  float logq = 0.f;   // only thread 0's copy is meaningful
  __syncthreads();

  #pragma unroll 1
  for (int s = 0; s < 64; ++s) {
    const int i = 2 * (s >> 3) + 1;
    const int j = 2 * (s & 7) + 1;

    // ---- phase 1: h1 tile (9x9x32) from x; tile (r,c) <-> field (i-4+r, j-4+c) ----
    if (tid < 288) {
      const int t_ic = tid / 9;
      const int r    = tid - t_ic * 9;
      const float bb = s_b1[t_ic];
      float a[9];
      #pragma unroll
      for (int c = 0; c < 9; ++c) a[c] = bb;
      #pragma unroll
      for (int ky = 0; ky < 5; ++ky) {
        const float* xr = &s_xf[(i + r + ky) * 28 + j];   // field row i-6+r+ky, cols j-6..j+6
        float xv[13];
        #pragma unroll
        for (int m = 0; m < 13; ++m) xv[m] = xr[m];
        #pragma unroll
        for (int kx = 0; kx < 5; ++kx) {
          const float w = s_w1[t_ic * 25 + ky * 5 + kx];
          #pragma unroll
          for (int c = 0; c < 9; ++c) a[c] = fmaf(xv[c + kx], w, a[c]);
        }
      }
      #pragma unroll
      for (int c = 0; c < 9; ++c) s_h1[t_ic][r][c] = lrelu(a[c]);
    }
    __syncthreads();

    // ---- phase 2: conv2 at 25 positions, 2 passes (15/10 accs), write-only merge ----
    // First contribution of acc(dy,dx) is at tr==dy (ky=0), kx=0: plain mul
    // (fmaf(a,b,0) == a*b bitwise) -- no acc-init movs. After the in-wave ic-pair
    // shfl merge, EVERY wave writes its pairsum to its own bank; no add stage, no
    // mid-pass barriers (pass p-ranges are disjoint; nothing reads s_buf until the
    // barrier after pass B).
#define CONV2_PASS(DYLO, DYHI, TRLO, TRHI, NACC)                                   \
    {                                                                              \
      float acc[NACC];                                                             \
      _Pragma("unroll")                                                            \
      for (int tr = (TRLO); tr <= (TRHI); ++tr) {                                  \
        const float4* rp = (const float4*)(&s_h1[ic][tr][0]);                      \
        const float4 ra = rp[0], rb = rp[1];                                       \
        const float r8 = s_h1[ic][tr][8];                                          \
        const float row[9] = {ra.x, ra.y, ra.z, ra.w, rb.x, rb.y, rb.z, rb.w, r8}; \
        _Pragma("unroll")                                                          \
        for (int dy = (DYLO); dy <= (DYHI); ++dy) {                                \
          const int ky = tr - dy;                                                  \
          if (ky < 0 || ky > 4) continue;   /* folds at compile time */            \
          _Pragma("unroll")                                                        \
          for (int kx = 0; kx < 5; ++kx) {                                         \
            const float w = w2r[ky * 5 + kx];                                      \
            _Pragma("unroll")                                                      \
            for (int dx = 0; dx < 5; ++dx) {                                       \
              const int pi = (dy - (DYLO)) * 5 + dx;                               \
              if (ky == 0 && kx == 0) acc[pi] = row[dx] * w;                       \
              else acc[pi] = fmaf(row[dx + kx], w, acc[pi]);                       \
            }                                                                      \
          }                                                                        \
        }                                                                          \
      }                                                                            \
      _Pragma("unroll")                                                            \
      for (int p = 0; p < (NACC); ++p) acc[p] += __shfl_xor(acc[p], 32, 64);       \
      if (lane < 32) {                                                             \
        _Pragma("unroll")                                                          \
        for (int p = 0; p < (NACC); ++p)                                           \
          s_buf[wv][((DYLO) * 5 + p) * 32 + lane] = acc[p];                        \
      }                                                                            \
    }

    CONV2_PASS(0, 2, 0, 6, 15)   // p = 0..14,  rows 0..6
    CONV2_PASS(3, 4, 3, 8, 10)   // p = 15..24, rows 3..8
#undef CONV2_PASS
    __syncthreads();

    // ---- phase 3: final a2 sum, lrelu, conv3 partials ----
    // t accumulates (b[v+8] + b[v]) for v ascending: identical chain to the old
    // add-stage (stored pair_{v+8} += pair_v, then t += s_buf[v]) -- the single
    // inner add is commuted, IEEE add is commutative => bit-identical.
    float v3 = 0.f;
    if (tid < 800) {
      float t = 0.f;
      #pragma unroll
      for (int v = 0; v < 8; ++v) t += (s_buf[v + 8][tid] + s_buf[v][tid]);
      t += s_b2[tid & 31];
      const float h2 = lrelu(t);
      v3 = h2 * s_w3[(tid & 31) * 25 + (tid >> 5)];   // w3[oc][pos]
    }
    #pragma unroll
    for (int m = 32; m >= 1; m >>= 1) v3 += __shfl_xor(v3, m, 64);
    if (lane == 0) s_c3[wv] = v3;
    __syncthreads();

    // ---- phase 4: sample (thread 0), update x field halo copies ----
    if (tid == 0) {
      float logit = b3v;
      #pragma unroll
      for (int v = 0; v < 16; ++v) logit += s_c3[v];
      const float pr   = 1.f / (1.f + expf(-logit));
      const float u    = s_u[s];
      const float samp = (u < pr) ? 1.f : -1.f;
      const int r1 = i + 6, c1 = j + 6;
      const int r2 = (i < 6) ? i + 22 : ((i >= 10) ? i - 10 : r1);
      const int c2 = (j < 6) ? j + 22 : ((j >= 10) ? j - 10 : c1);
      s_xf[r1 * 28 + c1] = samp; s_xf[r1 * 28 + c2] = samp;
      s_xf[r2 * 28 + c1] = samp; s_xf[r2 * 28 + c2] = samp;
      logq += (samp > 0.f) ? logf(pr + 1e-7f) : logf(1.f - pr + 1e-7f);
    }
    __syncthreads();
  }

  // ---------------- output ----------------
  if (tid < 256)
    out[bg * 256 + tid] = s_xf[((tid >> 4) + 6) * 28 + (tid & 15) + 6];
  if (tid == 0)
    out[B * 256 + bg] = logq;
}

extern "C" void kernel_launch(void* const* d_in, const int* in_sizes, int n_in,
                              void* d_out, int out_size, void* d_ws, size_t ws_size,
                              hipStream_t stream) {
  const float* gx  = (const float*)d_in[0];
  const float* gw1 = (const float*)d_in[1];
  const float* gb1 = (const float*)d_in[2];
  const float* gw2 = (const float*)d_in[3];
  const float* gb2 = (const float*)d_in[4];
  const float* gw3 = (const float*)d_in[5];
  const float* gb3 = (const float*)d_in[6];
  float* out = (float*)d_out;
  const int B = in_sizes[0] / 256;

  hipLaunchKernelGGL(van_kernel, dim3(B), dim3(1024), 0, stream,
                     gx, gw1, gb1, gw2, gb2, gw3, gb3, out, B);
}